// Round 7
// baseline (67.813 us; speedup 1.0000x reference)
//
#include <hip/hip_runtime.h>
#include <hip/hip_bf16.h>

typedef __bf16 bf16x8 __attribute__((ext_vector_type(8)));
typedef float  f32x4  __attribute__((ext_vector_type(4)));

#define B_SZ 1024
#define D_SZ 128
#define C_SZ 100000
#define CPAD 100096          // padded class rows (zero tail), 3128*32
#define BM 256
#define BN 32
#define NG 256               // C-tile groups (grid.x)
#define NCT 3128             // 100096/32

#define SCALE_F   64.0f
#define MARGIN_F  0.35f
#define CLIP_F    (1.0f - 1e-7f)
#define LOG2E_F   1.4426950408889634f
#define S_LOG2E_F (64.0f * 1.4426950408889634f)

__device__ __forceinline__ void gload_lds16(const void* g, void* l) {
    __builtin_amdgcn_global_load_lds(
        (const __attribute__((address_space(1))) void*)g,
        (__attribute__((address_space(3))) void*)l, 16, 0, 0);
}

// ---- Kernel A: L2-normalize W rows -> bf16 (+zero pad) + convert E -> bf16.
__global__ void norm_conv(const float* __restrict__ W, __bf16* __restrict__ Wb,
                          const float* __restrict__ E, __bf16* __restrict__ Eb) {
    const int b = blockIdx.x;
    if (b < 12512) {
        const int lane = threadIdx.x & 63;
        const int l32  = lane & 31;
        const int row  = b * 8 + ((threadIdx.x >> 6) << 1) + (lane >> 5);
        if (row < C_SZ) {
            float4 v = reinterpret_cast<const float4*>(W + (size_t)row * D_SZ)[l32];
            float ss = v.x * v.x + v.y * v.y + v.z * v.z + v.w * v.w;
            #pragma unroll
            for (int m = 1; m < 32; m <<= 1) ss += __shfl_xor(ss, m);
            float sc = 1.0f / fmaxf(sqrtf(ss), 1e-12f);
            union { __bf16 h[4]; uint2 u; } o;
            o.h[0] = (__bf16)(v.x * sc); o.h[1] = (__bf16)(v.y * sc);
            o.h[2] = (__bf16)(v.z * sc); o.h[3] = (__bf16)(v.w * sc);
            reinterpret_cast<uint2*>(Wb + (size_t)row * D_SZ)[l32] = o.u;
        } else {   // zero pad rows [C_SZ, CPAD)
            uint2 z; z.x = 0u; z.y = 0u;
            reinterpret_cast<uint2*>(Wb + (size_t)row * D_SZ)[l32] = z;
        }
    } else {
        const int i = (b - 12512) * 256 + threadIdx.x;   // 32768 float4
        float4 v = reinterpret_cast<const float4*>(E)[i];
        union { __bf16 h[4]; uint2 u; } o;
        o.h[0] = (__bf16)v.x; o.h[1] = (__bf16)v.y;
        o.h[2] = (__bf16)v.z; o.h[3] = (__bf16)v.w;
        reinterpret_cast<uint2*>(Eb)[i] = o.u;
    }
}

// ---- Kernel C: fused GEMM + exp-sum. Geometry chosen to minimize LDS pipe:
// wave tile 64x16 (ds_reads halve: MNK2/64 = 410MB) and BM=256 -> 4 bi groups
// (staging halves: 102MB). grid (NG=256, 4) = 1024 blocks = 4/CU.
// 512 threads = 8 waves (4wm x 2wn). LDS: 2 x 8KB sB + 2KB -> 18KB/block.
// VGPR state: a[4][4]=64 + acc[4]=16 + rowsum=16 = 96 (< R3's spilling 112).
__launch_bounds__(512, 4)
__global__ void gemm_lse(const __bf16* __restrict__ Eb, const __bf16* __restrict__ Wb,
                         float* __restrict__ P) {
    __shared__ __bf16 sB[2][BN * D_SZ];   // 2 x 8 KB, XOR-swizzled: byte ^= (row&7)<<4
    __shared__ float  rs[2][BM];          // 2 KB cross-wave reduce

    const int tid  = threadIdx.x;
    const int wave = tid >> 6;
    const int lane = tid & 63;
    const int g4   = lane >> 4;
    const int l15  = lane & 15;
    const int wm   = wave >> 1;           // 0..3 : 64-row slice
    const int wn   = wave & 1;            // 0..1 : 16-col slice
    const int g    = blockIdx.x;          // 0..255
    const int bi   = blockIdx.y;          // 0..3

    const int T = (NCT - g + NG - 1) / NG;   // 13 for g<56, else 12

    const char* wbase = reinterpret_cast<const char*>(Wb);
    // staging: 8KB tile = 512 threads x 16B, one gload per thread per tile.
    // p = tid*16; row = p>>8; source pre-swizzled to match read-side XOR.
    const int srcOff = ((tid >> 4) << 8) + ((((tid & 15) ^ ((tid >> 4) & 7))) << 4);
    const int ldsOff = wave << 10;        // wave-uniform dest base (lane x16 appended by HW)

    // ---- stage first B tile
    gload_lds16(wbase + (size_t)g * 8192 + srcOff,
                reinterpret_cast<char*>(sB[0]) + ldsOff);

    // ---- A fragments straight from global (once). 64 rows/wave -> 64 VGPR.
    bf16x8 a[4][4];
    {
        const char* ebase = reinterpret_cast<const char*>(Eb) + (size_t)bi * BM * 256;
        #pragma unroll
        for (int mi = 0; mi < 4; ++mi) {
            const char* pr = ebase + (wm * 64 + mi * 16 + l15) * 256 + g4 * 16;
            #pragma unroll
            for (int kk = 0; kk < 4; ++kk)
                a[mi][kk] = *reinterpret_cast<const bf16x8*>(pr + kk * 64);
        }
    }

    // hoisted ds_read offsets: row = wn*16 + l15 ; byte = (kk*64+g4*16)^((l15&7)<<4)
    const int rowb = (wn * 16 + l15) * 256;
    const int swz  = (l15 & 7) << 4;
    int kb[4];
    #pragma unroll
    for (int kk = 0; kk < 4; ++kk) kb[kk] = rowb + ((kk * 64 + g4 * 16) ^ swz);

    float rowsum[4][4] = {};   // [mi][r]

    __syncthreads();

    int cur = 0;
    for (int t = 0; t < T; ++t) {
        if (t + 1 < T)
            gload_lds16(wbase + (size_t)(g + (t + 1) * NG) * 8192 + srcOff,
                        reinterpret_cast<char*>(sB[cur ^ 1]) + ldsOff);

        const char* sBb = reinterpret_cast<const char*>(sB[cur]);
        f32x4 acc[4] = {};
        #pragma unroll
        for (int kk = 0; kk < 4; ++kk) {
            bf16x8 b = *reinterpret_cast<const bf16x8*>(sBb + kb[kk]);
            #pragma unroll
            for (int mi = 0; mi < 4; ++mi)
                acc[mi] = __builtin_amdgcn_mfma_f32_16x16x32_bf16(a[mi][kk], b, acc[mi], 0, 0, 0);
        }

        // epilogue: rowsum += exp2(min(x*92.33 - 92.33, 0)); upper clip = fmin,
        // lower clip free via underflow. (fmin NOT removable: unnormalized E
        // gives |dot| up to ~5 -> arg up to +370 would overflow.)
        #pragma unroll
        for (int mi = 0; mi < 4; ++mi)
            #pragma unroll
            for (int r = 0; r < 4; ++r)
                rowsum[mi][r] += __builtin_amdgcn_exp2f(
                    fminf(fmaf(acc[mi][r], S_LOG2E_F, -S_LOG2E_F), 0.0f));

        __syncthreads();   // prefetch landed; cur buffer free
        cur ^= 1;
    }

    // ---- reduce: 16 lanes (l15) in-wave, then 2 wave-cols via LDS
    #pragma unroll
    for (int mi = 0; mi < 4; ++mi) {
        #pragma unroll
        for (int r = 0; r < 4; ++r) {
            float s = rowsum[mi][r];
            s += __shfl_xor(s, 1);
            s += __shfl_xor(s, 2);
            s += __shfl_xor(s, 4);
            s += __shfl_xor(s, 8);
            rowsum[mi][r] = s;
        }
    }
    if (l15 == 0) {
        #pragma unroll
        for (int mi = 0; mi < 4; ++mi)
            #pragma unroll
            for (int r = 0; r < 4; ++r)
                rs[wn][wm * 64 + mi * 16 + g4 * 4 + r] = rowsum[mi][r];
    }
    __syncthreads();
    if (tid < BM)
        P[(size_t)g * B_SZ + bi * BM + tid] = rs[0][tid] + rs[1][tid];
}

// ---- Kernel D1: per-row S reduce (256 partials) + target dot + nll
__global__ void row_fin(const float* __restrict__ P, const __bf16* __restrict__ Eb,
                        const __bf16* __restrict__ Wb, const int* __restrict__ lab,
                        float* __restrict__ nll) {
    __shared__ float red[256];
    const int row = blockIdx.x;
    const int t   = threadIdx.x;

    red[t] = P[(size_t)t * B_SZ + row];
    __syncthreads();
    #pragma unroll
    for (int off = 128; off > 0; off >>= 1) {
        if (t < off) red[t] += red[t + off];
        __syncthreads();
    }
    const float S = red[0];
    __syncthreads();

    const int lb = lab[row];
    float d = 0.0f;
    if (t < 128) d = (float)Eb[row * D_SZ + t] * (float)Wb[(size_t)lb * D_SZ + t];
    red[t] = d;
    __syncthreads();
    #pragma unroll
    for (int off = 128; off > 0; off >>= 1) {
        if (t < off) red[t] += red[t + off];
        __syncthreads();
    }

    if (t == 0) {
        const float ct = red[0];
        const float cc = fminf(fmaxf(ct, -CLIP_F), CLIP_F);
        const float lt = SCALE_F * (cc - MARGIN_F);
        float Sadj = S - exp2f((SCALE_F * cc - SCALE_F) * LOG2E_F)
                       + exp2f((lt - SCALE_F) * LOG2E_F);
        nll[row] = SCALE_F + logf(Sadj) - lt;
    }
}

// ---- Kernel D2: mean over 1024 rows (shuffle-based)
__global__ void mean_k(const float* __restrict__ nll, float* __restrict__ out) {
    __shared__ float part[16];
    const int t = threadIdx.x;
    float v = nll[t];
    #pragma unroll
    for (int m = 1; m < 64; m <<= 1) v += __shfl_xor(v, m);
    if ((t & 63) == 0) part[t >> 6] = v;
    __syncthreads();
    if (t < 16) {
        float u = part[t];
        #pragma unroll
        for (int m = 1; m < 16; m <<= 1) u += __shfl_xor(u, m);
        if (t == 0) out[0] = u * (1.0f / 1024.0f);
    }
}

extern "C" void kernel_launch(void* const* d_in, const int* in_sizes, int n_in,
                              void* d_out, int out_size, void* d_ws, size_t ws_size,
                              hipStream_t stream) {
    const float* E   = (const float*)d_in[0];
    const int*   lab = (const int*)d_in[1];
    const float* W   = (const float*)d_in[2];
    float*       out = (float*)d_out;

    char* ws = (char*)d_ws;
    __bf16* Eb  = (__bf16*)ws;                                   // 262,144 B
    __bf16* Wb  = (__bf16*)(ws + 262144);                        // 25,624,576 B (CPAD rows)
    float*  P   = (float*)(ws + 262144 + 25624576);              // 1,048,576 B
    float*  nll = (float*)(ws + 262144 + 25624576 + 1048576);    // 4,096 B

    norm_conv<<<dim3(12640),   256, 0, stream>>>(W, Wb, E, Eb);
    gemm_lse <<<dim3(NG, 4),   512, 0, stream>>>(Eb, Wb, P);
    row_fin  <<<dim3(B_SZ),    256, 0, stream>>>(P, Eb, Wb, lab, nll);
    mean_k   <<<dim3(1),      1024, 0, stream>>>(nll, out);
}

// Round 8
// 63.535 us; speedup vs baseline: 1.0673x; 1.0673x over previous
//
#include <hip/hip_runtime.h>
#include <hip/hip_bf16.h>

typedef __bf16 bf16x8 __attribute__((ext_vector_type(8)));
typedef float  f32x4  __attribute__((ext_vector_type(4)));

#define B_SZ 1024
#define D_SZ 128
#define C_SZ 100000
#define CPAD 100096          // padded class rows (zero tail), 1564*64
#define BM 128
#define BN 64
#define NG 128               // C-tile groups (grid.x)
#define NCT 1564             // 100096/64

#define SCALE_F   64.0f
#define MARGIN_F  0.35f
#define CLIP_F    (1.0f - 1e-7f)
#define LOG2E_F   1.4426950408889634f
#define S_LOG2E_F (64.0f * 1.4426950408889634f)

__device__ __forceinline__ void gload_lds16(const void* g, void* l) {
    __builtin_amdgcn_global_load_lds(
        (const __attribute__((address_space(1))) void*)g,
        (__attribute__((address_space(3))) void*)l, 16, 0, 0);
}

// ---- Kernel A: L2-normalize W rows -> bf16 (+zero pad) + convert E -> bf16.
__global__ void norm_conv(const float* __restrict__ W, __bf16* __restrict__ Wb,
                          const float* __restrict__ E, __bf16* __restrict__ Eb) {
    const int b = blockIdx.x;
    if (b < 12512) {
        const int lane = threadIdx.x & 63;
        const int l32  = lane & 31;
        const int row  = b * 8 + ((threadIdx.x >> 6) << 1) + (lane >> 5);
        if (row < C_SZ) {
            float4 v = reinterpret_cast<const float4*>(W + (size_t)row * D_SZ)[l32];
            float ss = v.x * v.x + v.y * v.y + v.z * v.z + v.w * v.w;
            #pragma unroll
            for (int m = 1; m < 32; m <<= 1) ss += __shfl_xor(ss, m);
            float sc = 1.0f / fmaxf(sqrtf(ss), 1e-12f);
            union { __bf16 h[4]; uint2 u; } o;
            o.h[0] = (__bf16)(v.x * sc); o.h[1] = (__bf16)(v.y * sc);
            o.h[2] = (__bf16)(v.z * sc); o.h[3] = (__bf16)(v.w * sc);
            reinterpret_cast<uint2*>(Wb + (size_t)row * D_SZ)[l32] = o.u;
        } else {   // zero pad rows [C_SZ, CPAD)
            uint2 z; z.x = 0u; z.y = 0u;
            reinterpret_cast<uint2*>(Wb + (size_t)row * D_SZ)[l32] = z;
        }
    } else {
        const int i = (b - 12512) * 256 + threadIdx.x;   // 32768 float4
        float4 v = reinterpret_cast<const float4*>(E)[i];
        union { __bf16 h[4]; uint2 u; } o;
        o.h[0] = (__bf16)v.x; o.h[1] = (__bf16)v.y;
        o.h[2] = (__bf16)v.z; o.h[3] = (__bf16)v.w;
        reinterpret_cast<uint2*>(Eb)[i] = o.u;
    }
}

// ---- Kernel C: fused GEMM + exp-sum with T3/T4 pipeline:
// 3 LDS buffers, counted s_waitcnt vmcnt(2) (never 0 in-loop), ONE raw
// s_barrier per tile, stage(t+2) issued right after the barrier.
// grid (NG=128, 8 bi) = 1024 blocks. 512 thr = 8 waves 2wm x 4wn,
// wave tile 64 rows x 16 cols (B-read redundancy 2).
// VGPR state: a[4][4]=64 + acc[4]=16 + rowsum[4][4]=16 + addr ~20 ~ 118.
__launch_bounds__(512, 3)
__global__ void gemm_lse(const __bf16* __restrict__ Eb, const __bf16* __restrict__ Wb,
                         float* __restrict__ P) {
    __shared__ __bf16 sB[3][BN * D_SZ];   // 3 x 16 KB, XOR-swizzled: byte ^= (row&7)<<4
    __shared__ float  rs[4][BM];          // 2 KB cross-wave reduce

    const int tid  = threadIdx.x;
    const int wave = tid >> 6;
    const int lane = tid & 63;
    const int g4   = lane >> 4;
    const int l15  = lane & 15;
    const int wm   = wave >> 2;           // 0..1 : 64-row slice
    const int wn   = wave & 3;            // 0..3 : 16-col slice
    const int g    = blockIdx.x;          // 0..127
    const int bi   = blockIdx.y;          // 0..7

    const int T = (NCT - g + NG - 1) / NG;   // 13 for g<28, else 12

    const char* wbase = reinterpret_cast<const char*>(Wb);
    // staging: 16KB tile = 2 passes x (512 thr x 16B); source pre-swizzled.
    const int srcOff = ((tid >> 4) << 8) + ((((tid & 15) ^ ((tid >> 4) & 7))) << 4);
    const int ldsOff = wave << 10;        // wave-uniform dest base within 8KB pass

#define STAGE(TI, BUF)                                                         \
    {                                                                          \
        const size_t _o = (size_t)(TI) * 16384;                                \
        char* _d = reinterpret_cast<char*>(BUF);                               \
        gload_lds16(wbase + _o + srcOff,        _d + ldsOff);                  \
        gload_lds16(wbase + _o + 8192 + srcOff, _d + 8192 + ldsOff);           \
    }

    // ---- A fragments first (oldest VMEM; keeps loop vmcnt counting exact)
    bf16x8 a[4][4];
    {
        const char* ebase = reinterpret_cast<const char*>(Eb) + (size_t)bi * BM * 256;
        #pragma unroll
        for (int mi = 0; mi < 4; ++mi) {
            const char* pr = ebase + (wm * 64 + mi * 16 + l15) * 256 + g4 * 16;
            #pragma unroll
            for (int kk = 0; kk < 4; ++kk)
                a[mi][kk] = *reinterpret_cast<const bf16x8*>(pr + kk * 64);
        }
    }

    // ---- prologue: stage tiles 0 and 1
    STAGE(g, sB[0]);
    if (T > 1) STAGE(g + NG, sB[1]);

    // hoisted ds_read offsets: row = wn*16 + l15 ; byte = (kk*64+g4*16)^((l15&7)<<4)
    const int rowb = (wn * 16 + l15) * 256;
    const int swz  = (l15 & 7) << 4;
    int kb[4];
    #pragma unroll
    for (int kk = 0; kk < 4; ++kk) kb[kk] = rowb + ((kk * 64 + g4 * 16) ^ swz);

    float rowsum[4][4] = {};   // [mi][r]

    const __bf16* pcur   = sB[0];
    const __bf16* pnext  = sB[1];
    const __bf16* pnext2 = sB[2];

    for (int t = 0; t < T; ++t) {
        // tile t landed (tile t+1's 2 loads may stay in flight; no drain)
        if (t + 1 < T) asm volatile("s_waitcnt vmcnt(2)" ::: "memory");
        else           asm volatile("s_waitcnt vmcnt(0)" ::: "memory");
        __builtin_amdgcn_s_barrier();
        // stage t+2 into the buffer everyone finished reading at iter t-1
        if (t + 2 < T) STAGE(g + (t + 2) * NG, const_cast<__bf16*>(pnext2));

        const char* sBb = reinterpret_cast<const char*>(pcur);
        f32x4 acc[4] = {};
        __builtin_amdgcn_s_setprio(1);
        #pragma unroll
        for (int kk = 0; kk < 4; ++kk) {
            bf16x8 b = *reinterpret_cast<const bf16x8*>(sBb + kb[kk]);
            #pragma unroll
            for (int mi = 0; mi < 4; ++mi)
                acc[mi] = __builtin_amdgcn_mfma_f32_16x16x32_bf16(a[mi][kk], b, acc[mi], 0, 0, 0);
        }
        __builtin_amdgcn_s_setprio(0);

        // epilogue: rowsum += exp2(min(x*92.33 - 92.33, 0)); overlaps other
        // waves' MFMA. Lower clip free (underflow), upper clip = the fmin.
        #pragma unroll
        for (int mi = 0; mi < 4; ++mi)
            #pragma unroll
            for (int r = 0; r < 4; ++r)
                rowsum[mi][r] += __builtin_amdgcn_exp2f(
                    fminf(fmaf(acc[mi][r], S_LOG2E_F, -S_LOG2E_F), 0.0f));

        const __bf16* tmp = pcur; pcur = pnext; pnext = pnext2; pnext2 = tmp;
    }

    // ---- reduce: 16 lanes (l15) in-wave, then 4 wave-cols via LDS
    #pragma unroll
    for (int mi = 0; mi < 4; ++mi) {
        #pragma unroll
        for (int r = 0; r < 4; ++r) {
            float s = rowsum[mi][r];
            s += __shfl_xor(s, 1);
            s += __shfl_xor(s, 2);
            s += __shfl_xor(s, 4);
            s += __shfl_xor(s, 8);
            rowsum[mi][r] = s;
        }
    }
    __syncthreads();   // everyone past the tile loop before rs reuse
    if (l15 == 0) {
        #pragma unroll
        for (int mi = 0; mi < 4; ++mi)
            #pragma unroll
            for (int r = 0; r < 4; ++r)
                rs[wn][wm * 64 + mi * 16 + g4 * 4 + r] = rowsum[mi][r];
    }
    __syncthreads();
    if (tid < BM)
        P[(size_t)g * B_SZ + bi * BM + tid] =
            (rs[0][tid] + rs[1][tid]) + (rs[2][tid] + rs[3][tid]);
#undef STAGE
}

// ---- Kernel D1: per-row S reduce (NG partials) + target dot + nll
__global__ void row_fin(const float* __restrict__ P, const __bf16* __restrict__ Eb,
                        const __bf16* __restrict__ Wb, const int* __restrict__ lab,
                        float* __restrict__ nll) {
    __shared__ float red[256];
    const int row = blockIdx.x;
    const int t   = threadIdx.x;

    red[t] = (t < NG) ? P[(size_t)t * B_SZ + row] : 0.0f;
    __syncthreads();
    #pragma unroll
    for (int off = 128; off > 0; off >>= 1) {
        if (t < off) red[t] += red[t + off];
        __syncthreads();
    }
    const float S = red[0];
    __syncthreads();

    const int lb = lab[row];
    float d = 0.0f;
    if (t < 128) d = (float)Eb[row * D_SZ + t] * (float)Wb[(size_t)lb * D_SZ + t];
    red[t] = d;
    __syncthreads();
    #pragma unroll
    for (int off = 128; off > 0; off >>= 1) {
        if (t < off) red[t] += red[t + off];
        __syncthreads();
    }

    if (t == 0) {
        const float ct = red[0];
        const float cc = fminf(fmaxf(ct, -CLIP_F), CLIP_F);
        const float lt = SCALE_F * (cc - MARGIN_F);
        float Sadj = S - exp2f((SCALE_F * cc - SCALE_F) * LOG2E_F)
                       + exp2f((lt - SCALE_F) * LOG2E_F);
        nll[row] = SCALE_F + logf(Sadj) - lt;
    }
}

// ---- Kernel D2: mean over 1024 rows (shuffle-based)
__global__ void mean_k(const float* __restrict__ nll, float* __restrict__ out) {
    __shared__ float part[16];
    const int t = threadIdx.x;
    float v = nll[t];
    #pragma unroll
    for (int m = 1; m < 64; m <<= 1) v += __shfl_xor(v, m);
    if ((t & 63) == 0) part[t >> 6] = v;
    __syncthreads();
    if (t < 16) {
        float u = part[t];
        #pragma unroll
        for (int m = 1; m < 16; m <<= 1) u += __shfl_xor(u, m);
        if (t == 0) out[0] = u * (1.0f / 1024.0f);
    }
}

extern "C" void kernel_launch(void* const* d_in, const int* in_sizes, int n_in,
                              void* d_out, int out_size, void* d_ws, size_t ws_size,
                              hipStream_t stream) {
    const float* E   = (const float*)d_in[0];
    const int*   lab = (const int*)d_in[1];
    const float* W   = (const float*)d_in[2];
    float*       out = (float*)d_out;

    char* ws = (char*)d_ws;
    __bf16* Eb  = (__bf16*)ws;                                   // 262,144 B
    __bf16* Wb  = (__bf16*)(ws + 262144);                        // 25,624,576 B (CPAD rows)
    float*  P   = (float*)(ws + 262144 + 25624576);              // 524,288 B
    float*  nll = (float*)(ws + 262144 + 25624576 + 524288);     // 4,096 B

    norm_conv<<<dim3(12640),   256, 0, stream>>>(W, Wb, E, Eb);
    gemm_lse <<<dim3(NG, 8),   512, 0, stream>>>(Eb, Wb, P);
    row_fin  <<<dim3(B_SZ),    256, 0, stream>>>(P, Eb, Wb, lab, nll);
    mean_k   <<<dim3(1),      1024, 0, stream>>>(nll, out);
}